// Round 4
// baseline (253.496 us; speedup 1.0000x reference)
//
#include <hip/hip_runtime.h>

// EdgeAttention: 4-scale 1x1-conv projection + pairwise per-pixel cosine + 4x4 softmax.
// Round 4: (a) proj GEMM with barrier-free K-loop — W and F fragments loaded directly
// from global into MFMA registers (W pre-packed, L2-resident; F read once, HBM-bound),
// epilogue-only LDS used to transpose unit vectors to pixel-major [b][l][c] bf16.
// (b) pair pass reads pixel-major rows with 16-B vector loads, fuses all j>i dots per
// i-pass, per-lane accumulation + single block reduction + atomics.
// Fragment semantics identical to round 3 (validated absmax 0.0).

#define CCH 256

typedef __attribute__((ext_vector_type(8))) short short8;
typedef __attribute__((ext_vector_type(4))) short short4_;
typedef __attribute__((ext_vector_type(4))) float float4_;

__device__ inline short f2bf(float x) {   // round-to-nearest-even fp32 -> bf16
    union { float f; unsigned u; } c; c.f = x;
    unsigned u = c.u + 0x7FFFu + ((c.u >> 16) & 1u);
    return (short)(u >> 16);
}
__device__ inline float bf2f(short b) {
    union { unsigned u; float f; } c; c.u = ((unsigned)(unsigned short)b) << 16;
    return c.f;
}

// ---------- W pack: fp32 [o][c] -> bf16 [ks][o][kk] (ks = c/32, kk = c%32) ----------
__global__ void pack_w(const float* __restrict__ w0, const float* __restrict__ w1,
                       const float* __restrict__ w2, const float* __restrict__ w3,
                       short* __restrict__ wp) {
    const float* W[4] = {w0, w1, w2, w3};
    const float* Ws = W[blockIdx.y];
    short* out = wp + (size_t)blockIdx.y * 65536;
    int base = (blockIdx.x * 256 + threadIdx.x) * 8;   // grid.x=32 -> 65536 shorts
    int kk0 = base & 31;
    int o   = (base >> 5) & 255;
    int ks  = base >> 13;
    const float* src = Ws + o * CCH + ks * 32 + kk0;
    short8 v;
#pragma unroll
    for (int j = 0; j < 8; ++j) v[j] = f2bf(src[j]);
    *(short8*)(out + base) = v;
}

// ---------- Projection GEMM (bf16 MFMA) + bias + L2-normalize + transpose ----------
// 256 thr = 4 waves; block computes 256 out-ch for 64 pixels of one (scale,b).
// Wave w owns pixels [tile*64 + w*16, +16). Main loop has NO LDS and NO barriers:
// A (W) fragments load straight from packed global (L2-hot), B (F) fragments load
// straight from HBM. Epilogue transposes to pixel-major u[b][l][c] bf16 via LDS.
#define TPITCH 264   // epilogue LDS row pitch in shorts (256 + 8 pad)
__global__ __launch_bounds__(256) void proj_norm2(
    const float* __restrict__ f0, const float* __restrict__ f1,
    const float* __restrict__ f2, const float* __restrict__ f3,
    const short* __restrict__ wp,
    const float* __restrict__ b0, const float* __restrict__ b1,
    const float* __restrict__ b2, const float* __restrict__ b3,
    short* __restrict__ u0, short* __restrict__ u1,
    short* __restrict__ u2, short* __restrict__ u3)
{
    __shared__ short Ut[64 * TPITCH];   // 33 KB, epilogue transpose only

    const int blk = blockIdx.x;
    int s, b, tile, L;
    const float* F; const float* bias; short* U;
    if (blk < 800)       { s = 0; int r = blk;        b = r / 100; tile = r % 100; L = 6400; F = f0; bias = b0; U = u0; }
    else if (blk < 1000) { s = 1; int r = blk - 800;  b = r / 25;  tile = r % 25;  L = 1600; F = f1; bias = b1; U = u1; }
    else if (blk < 1056) { s = 2; int r = blk - 1000; b = r / 7;   tile = r % 7;   L = 400;  F = f2; bias = b2; U = u2; }
    else                 { s = 3; int r = blk - 1056; b = r / 2;   tile = r % 2;   L = 100;  F = f3; bias = b3; U = u3; }

    const int t    = threadIdx.x;
    const int lane = t & 63;
    const int wav  = t >> 6;
    const int ln   = lane & 15;
    const int quad = lane >> 4;
    const int pixbase = tile * 64;
    const float* Fb = F + (size_t)b * CCH * L;
    const short* wbase = wp + (size_t)s * 65536;

    const int gpix = pixbase + wav * 16 + ln;
    const bool pin = gpix < L;
    const int gl = pin ? gpix : 0;      // clamp to stay in-bounds; value zeroed below

    float4_ acc[16];
#pragma unroll
    for (int i = 0; i < 16; ++i) acc[i] = (float4_){0.f, 0.f, 0.f, 0.f};

    for (int ks = 0; ks < 8; ++ks) {
        // B fragment: 8 channels (ks*32+quad*8 ..+7) of this lane's pixel, fp32->bf16.
        const float* fs = Fb + (size_t)(ks * 32 + quad * 8) * L + gl;
        short8 bfrag;
#pragma unroll
        for (int j = 0; j < 8; ++j) {
            float x = fs[(size_t)j * L];
            bfrag[j] = pin ? f2bf(x) : (short)0;
        }
        // A fragments direct from packed W: lane (ln,quad) reads 16 B per mt tile.
#pragma unroll
        for (int mt = 0; mt < 16; ++mt) {
            short8 afrag = *(const short8*)(wbase + ks * 8192 + (mt * 16 + ln) * 32 + quad * 8);
            acc[mt] = __builtin_amdgcn_mfma_f32_16x16x32_bf16(afrag, bfrag, acc[mt], 0, 0, 0);
        }
    }

    // Epilogue. C/D layout (validated): col(pixel)=lane&15, row(channel)=quad*4+reg.
    float ss = 0.f;
#pragma unroll
    for (int mt = 0; mt < 16; ++mt) {
        float4_ bv = *(const float4_*)(bias + mt * 16 + quad * 4);
#pragma unroll
        for (int r = 0; r < 4; ++r) {
            float v = acc[mt][r] + bv[r];
            acc[mt][r] = v;
            ss += v * v;
        }
    }
    ss += __shfl_xor(ss, 16);
    ss += __shfl_xor(ss, 32);
    const float inv = 1.f / sqrtf(fmaxf(ss, 1e-24f));

    // Transpose through LDS: Ut[px_local][ch], pitch 264.
    const int pxl = wav * 16 + ln;
#pragma unroll
    for (int mt = 0; mt < 16; ++mt) {
        short4_ v;
#pragma unroll
        for (int r = 0; r < 4; ++r) v[r] = f2bf(acc[mt][r] * inv);
        *(short4_*)(&Ut[pxl * TPITCH + mt * 16 + quad * 4]) = v;
    }
    __syncthreads();

    // Coalesced pixel-major store: thread t writes 64 ch of pixel t>>2.
    {
        const int opx = t >> 2;
        const int c0 = (t & 3) * 64;
        const int gpx = pixbase + opx;
        if (gpx < L) {
            short* dst = U + ((size_t)b * L + gpx) * CCH + c0;
#pragma unroll
            for (int k = 0; k < 8; ++k)
                *(short8*)(dst + k * 8) = *(const short8*)(&Ut[opx * TPITCH + c0 + k * 8]);
        }
    }
}

// ---------- Pair pass: fused dots of scale i against all j>i (pixel-major u) ----------
// Lane = (pg = lane>>3: pixel-in-group-of-8, sub = lane&7: 32-ch chunk).
// Each wave iterates groups with stride 200 (= 50 blocks * 4 waves per (i,b)).
template <int I>
__device__ inline void pair_body(const short* __restrict__ ui,
                                 const short* __restrict__ uu1,
                                 const short* __restrict__ uu2,
                                 const short* __restrict__ uu3,
                                 int b, int wave_id, int pg, int sub, float* acc) {
    constexpr int RI = 80 >> I;
    constexpr int LI = RI * RI;
    constexpr int NG = LI / 8;
    const short* __restrict__ uj[3] = {uu1, uu2, uu3};   // uj[d-1] = scale I+d

    for (int g = wave_id; g < NG; g += 200) {
        const int px = g * 8 + pg;
        const int h = px / RI;            // constexpr divisor -> magic mul
        const int w = px - h * RI;
        const short* pa = ui + ((size_t)(b * LI + px)) * CCH + sub * 32;
        float a[32];
#pragma unroll
        for (int k = 0; k < 4; ++k) {
            short8 v = *(const short8*)(pa + k * 8);
#pragma unroll
            for (int e = 0; e < 8; ++e) a[k * 8 + e] = bf2f(v[e]);
        }
#pragma unroll
        for (int d = 1; d <= 3 - I; ++d) {
            const int RJ = RI >> d;
            const int LJ = RJ * RJ;
            const int pxj = (h >> d) * RJ + (w >> d);
            const short* pb = uj[d - 1] + ((size_t)(b * LJ + pxj)) * CCH + sub * 32;
            float s = 0.f;
#pragma unroll
            for (int k = 0; k < 4; ++k) {
                short8 v = *(const short8*)(pb + k * 8);
#pragma unroll
                for (int e = 0; e < 8; ++e) s += a[k * 8 + e] * bf2f(v[e]);
            }
            acc[d - 1] += s;
        }
    }
}

__global__ __launch_bounds__(256) void pair_dots(
    const short* __restrict__ u0, const short* __restrict__ u1,
    const short* __restrict__ u2, const short* __restrict__ u3,
    float* __restrict__ sums) {
    const int i = blockIdx.y;          // fine scale of the pass: 0,1,2
    const int b = blockIdx.z;
    const int t = threadIdx.x;
    const int lane = t & 63;
    const int wav = t >> 6;
    const int wave_id = blockIdx.x * 4 + wav;   // 0..199
    const int pg = lane >> 3;
    const int sub = lane & 7;

    float acc[3] = {0.f, 0.f, 0.f};
    if (i == 0)      pair_body<0>(u0, u1, u2, u3, b, wave_id, pg, sub, acc);
    else if (i == 1) pair_body<1>(u1, u2, u3, u3, b, wave_id, pg, sub, acc);
    else             pair_body<2>(u2, u3, u3, u3, b, wave_id, pg, sub, acc);

    __shared__ float red[4][3];
#pragma unroll
    for (int p = 0; p < 3; ++p) {
        float v = acc[p];
        v += __shfl_xor(v, 1);  v += __shfl_xor(v, 2);  v += __shfl_xor(v, 4);
        v += __shfl_xor(v, 8);  v += __shfl_xor(v, 16); v += __shfl_xor(v, 32);
        if (lane == 0) red[wav][p] = v;
    }
    __syncthreads();
    const int npairs = 3 - i;
    const int base = (i == 0) ? 0 : (i == 1) ? 3 : 5;
    if (t < npairs) {
        float s = red[0][t] + red[1][t] + red[2][t] + red[3][t];
        atomicAdd(&sums[b * 6 + base + t], s);
    }
}

// ---------- Softmax over j for each (b,i) row ----------
__global__ void softmax4(const float* __restrict__ sums, float* __restrict__ out) {
    int t = threadIdx.x;
    if (t >= 128) return;
    int b = t >> 4, i = (t >> 2) & 3, j = t & 3;
    float a[4];
#pragma unroll
    for (int jj = 0; jj < 4; ++jj) {
        if (jj == i) { a[jj] = 1.0f; continue; }
        int lo = i < jj ? i : jj;
        int hi = i < jj ? jj : i;
        int pidx;
        if (lo == 0) pidx = hi - 1;          // (0,1)=0 (0,2)=1 (0,3)=2
        else if (lo == 1) pidx = 1 + hi;     // (1,2)=3 (1,3)=4
        else pidx = 5;                       // (2,3)=5
        int rf = 80 >> lo;
        a[jj] = sums[b * 6 + pidx] / (float)(rf * rf);
    }
    float m = fmaxf(fmaxf(a[0], a[1]), fmaxf(a[2], a[3]));
    float e0 = expf(a[0] - m), e1 = expf(a[1] - m), e2 = expf(a[2] - m), e3 = expf(a[3] - m);
    float sum = e0 + e1 + e2 + e3;
    float ev = (j == 0) ? e0 : (j == 1) ? e1 : (j == 2) ? e2 : e3;
    out[t] = ev / sum;
}

extern "C" void kernel_launch(void* const* d_in, const int* in_sizes, int n_in,
                              void* d_out, int out_size, void* d_ws, size_t ws_size,
                              hipStream_t stream) {
    // setup_inputs dict insertion order: f0,w0,b0, f1,w1,b1, f2,w2,b2, f3,w3,b3
    const float* f[4]  = {(const float*)d_in[0], (const float*)d_in[3],
                          (const float*)d_in[6], (const float*)d_in[9]};
    const float* w[4]  = {(const float*)d_in[1], (const float*)d_in[4],
                          (const float*)d_in[7], (const float*)d_in[10]};
    const float* bs[4] = {(const float*)d_in[2], (const float*)d_in[5],
                          (const float*)d_in[8], (const float*)d_in[11]};

    const int Ls[4] = {6400, 1600, 400, 100};
    char* ws = (char*)d_ws;
    size_t off = 0;
    short* u[4];
    for (int s = 0; s < 4; ++s) {
        u[s] = (short*)(ws + off);
        off += (size_t)8 * CCH * Ls[s] * sizeof(short);
    }
    short* wp = (short*)(ws + off); off += 4 * 65536 * sizeof(short);
    float* sums = (float*)(ws + off);   // 48 floats

    hipMemsetAsync(sums, 0, 64 * sizeof(float), stream);

    pack_w<<<dim3(32, 4), 256, 0, stream>>>(w[0], w[1], w[2], w[3], wp);

    proj_norm2<<<1072, 256, 0, stream>>>(f[0], f[1], f[2], f[3], wp,
                                         bs[0], bs[1], bs[2], bs[3],
                                         u[0], u[1], u[2], u[3]);

    pair_dots<<<dim3(50, 3, 8), 256, 0, stream>>>(u[0], u[1], u[2], u[3], sums);

    softmax4<<<1, 128, 0, stream>>>(sums, (float*)d_out);
}

// Round 5
// 175.787 us; speedup vs baseline: 1.4421x; 1.4421x over previous
//
#include <hip/hip_runtime.h>

// EdgeAttention: 4-scale 1x1-conv projection + pairwise per-pixel cosine + 4x4 softmax.
// Round 5: recombination of measured-best parts.
//  - proj: round-3 LDS-staged MFMA K-loop (50 us measured; W slice staged once per
//    block and shared by 4 waves — round 4 proved per-wave global W loads are 3x worse)
//  - epilogue: round-4 LDS transpose -> pixel-major u[b][l][c] bf16 (validated)
//  - pair pass: round-4 fused vectorized pair_dots (validated)
// Nearest upsample == block replication (src = dst >> d): pair (i,j) mean over finer
// grid. Diagonal attn == 1 exactly.

#define CCH 256

typedef __attribute__((ext_vector_type(8))) short short8;
typedef __attribute__((ext_vector_type(4))) short short4_;
typedef __attribute__((ext_vector_type(4))) float float4_;

__device__ inline short f2bf(float x) {   // round-to-nearest-even fp32 -> bf16
    union { float f; unsigned u; } c; c.f = x;
    unsigned u = c.u + 0x7FFFu + ((c.u >> 16) & 1u);
    return (short)(u >> 16);
}
__device__ inline float bf2f(short b) {
    union { unsigned u; float f; } c; c.u = ((unsigned)(unsigned short)b) << 16;
    return c.f;
}

// ---------- W pack: fp32 [o][c] -> bf16 [ks][o][kk] (ks = c/32, kk = c%32) ----------
__global__ void pack_w(const float* __restrict__ w0, const float* __restrict__ w1,
                       const float* __restrict__ w2, const float* __restrict__ w3,
                       short* __restrict__ wp) {
    const float* W[4] = {w0, w1, w2, w3};
    const float* Ws = W[blockIdx.y];
    short* out = wp + (size_t)blockIdx.y * 65536;
    int base = (blockIdx.x * 256 + threadIdx.x) * 8;   // grid.x=32 -> 65536 shorts
    int kk0 = base & 31;
    int o   = (base >> 5) & 255;
    int ks  = base >> 13;
    const float* src = Ws + o * CCH + ks * 32 + kk0;
    short8 v;
#pragma unroll
    for (int j = 0; j < 8; ++j) v[j] = f2bf(src[j]);
    *(short8*)(out + base) = v;
}

// ---------- Projection GEMM (bf16 MFMA, LDS-staged) + bias + normalize + transpose ----
// 256 thr = 4 waves; block computes 256 out-ch for 64 pixels of one (scale,b).
// K-loop identical to round 3 (measured 50 us). Epilogue from round 4 (validated):
// pixel-major u[b][l][c] bf16 store via LDS transpose (Ut aliases Wt/Ft past a barrier).
#define LDP 56       // K-loop LDS row pitch in shorts: 112 B, near-conflict-free
#define TPITCH 264   // epilogue transpose pitch in shorts (256 + 8 pad)
__global__ __launch_bounds__(256) void proj_norm(
    const float* __restrict__ f0, const float* __restrict__ f1,
    const float* __restrict__ f2, const float* __restrict__ f3,
    const short* __restrict__ wp,
    const float* __restrict__ b0, const float* __restrict__ b1,
    const float* __restrict__ b2, const float* __restrict__ b3,
    short* __restrict__ u0, short* __restrict__ u1,
    short* __restrict__ u2, short* __restrict__ u3)
{
    __shared__ __align__(16) char smem[36864];
    short* Wt = (short*)smem;                 // [256][LDP]  28672 B
    short* Ft = (short*)(smem + 28672);       // [64][LDP]    7168 B
    short* Ut = (short*)smem;                 // epilogue alias: [64][TPITCH] 33792 B

    const int blk = blockIdx.x;
    int s, b, tile, L;
    const float* F; const float* bias; short* U;
    if (blk < 800)       { s = 0; int r = blk;        b = r / 100; tile = r % 100; L = 6400; F = f0; bias = b0; U = u0; }
    else if (blk < 1000) { s = 1; int r = blk - 800;  b = r / 25;  tile = r % 25;  L = 1600; F = f1; bias = b1; U = u1; }
    else if (blk < 1056) { s = 2; int r = blk - 1000; b = r / 7;   tile = r % 7;   L = 400;  F = f2; bias = b2; U = u2; }
    else                 { s = 3; int r = blk - 1056; b = r / 2;   tile = r % 2;   L = 100;  F = f3; bias = b3; U = u3; }

    const int t    = threadIdx.x;
    const int lane = t & 63;
    const int wav  = t >> 6;
    const int ln   = lane & 15;
    const int quad = lane >> 4;
    const int pixbase = tile * 64;
    const float* Fb = F + (size_t)b * CCH * L;
    const short* wbase = wp + (size_t)s * 65536;

    float4_ acc[16];
#pragma unroll
    for (int i = 0; i < 16; ++i) acc[i] = (float4_){0.f, 0.f, 0.f, 0.f};

    // F staging: thread loads 8 channels (fk0..fk0+7) of its pixel, packs one short8.
    const int fpix = t & 63;
    const int fk0  = (t >> 6) * 8;
    const int gpix0 = pixbase + fpix;
    const bool pin = gpix0 < L;

    for (int ks = 0; ks < 8; ++ks) {
        __syncthreads();
        // W slice: contiguous 16 KB copy (pre-packed), LDS rows [o][kk] padded to LDP.
        {
            const short8* src = (const short8*)(wbase + ks * 8192);
#pragma unroll
            for (int it = 0; it < 4; ++it) {
                int idx = it * 256 + t;
                short8 v = src[idx];
                *(short8*)(&Wt[(idx >> 2) * LDP + (idx & 3) * 8]) = v;
            }
        }
        // F slice: [pixel][kk] rows (B-fragment layout), fp32->bf16 on the fly.
        {
            const float* fs = Fb + (size_t)(ks * 32 + fk0) * L + gpix0;
            short8 v;
#pragma unroll
            for (int j = 0; j < 8; ++j)
                v[j] = f2bf(pin ? fs[(size_t)j * L] : 0.f);
            *(short8*)(&Ft[fpix * LDP + fk0]) = v;
        }
        __syncthreads();
        short8 bfrag = *(const short8*)(&Ft[(wav * 16 + ln) * LDP + quad * 8]);
#pragma unroll
        for (int mt = 0; mt < 16; ++mt) {
            short8 afrag = *(const short8*)(&Wt[(mt * 16 + ln) * LDP + quad * 8]);
            acc[mt] = __builtin_amdgcn_mfma_f32_16x16x32_bf16(afrag, bfrag, acc[mt], 0, 0, 0);
        }
    }

    // Epilogue. C/D layout (validated): col(pixel)=lane&15, row(channel)=quad*4+reg.
    float ss = 0.f;
#pragma unroll
    for (int mt = 0; mt < 16; ++mt) {
        float4_ bv = *(const float4_*)(bias + mt * 16 + quad * 4);
#pragma unroll
        for (int r = 0; r < 4; ++r) {
            float v = acc[mt][r] + bv[r];
            acc[mt][r] = v;
            ss += v * v;
        }
    }
    ss += __shfl_xor(ss, 16);
    ss += __shfl_xor(ss, 32);
    const float inv = 1.f / sqrtf(fmaxf(ss, 1e-24f));

    __syncthreads();   // Ut aliases Wt/Ft — wait for all K-loop LDS reads to finish

    // Transpose through LDS: Ut[px_local][ch], pitch TPITCH.
    const int pxl = wav * 16 + ln;
#pragma unroll
    for (int mt = 0; mt < 16; ++mt) {
        short4_ v;
#pragma unroll
        for (int r = 0; r < 4; ++r) v[r] = f2bf(acc[mt][r] * inv);
        *(short4_*)(&Ut[pxl * TPITCH + mt * 16 + quad * 4]) = v;
    }
    __syncthreads();

    // Coalesced pixel-major store: thread t writes 64 ch of pixel t>>2.
    {
        const int opx = t >> 2;
        const int c0 = (t & 3) * 64;
        const int gpx = pixbase + opx;
        if (gpx < L) {
            short* dst = U + ((size_t)b * L + gpx) * CCH + c0;
#pragma unroll
            for (int k = 0; k < 8; ++k)
                *(short8*)(dst + k * 8) = *(const short8*)(&Ut[opx * TPITCH + c0 + k * 8]);
        }
    }
}

// ---------- Pair pass: fused dots of scale i against all j>i (pixel-major u) ----------
// Lane = (pg = lane>>3: pixel-in-group-of-8, sub = lane&7: 32-ch chunk).
template <int I>
__device__ inline void pair_body(const short* __restrict__ ui,
                                 const short* __restrict__ uu1,
                                 const short* __restrict__ uu2,
                                 const short* __restrict__ uu3,
                                 int b, int wave_id, int pg, int sub, float* acc) {
    constexpr int RI = 80 >> I;
    constexpr int LI = RI * RI;
    constexpr int NG = LI / 8;
    const short* __restrict__ uj[3] = {uu1, uu2, uu3};   // uj[d-1] = scale I+d

    for (int g = wave_id; g < NG; g += 200) {
        const int px = g * 8 + pg;
        const int h = px / RI;            // constexpr divisor -> magic mul
        const int w = px - h * RI;
        const short* pa = ui + ((size_t)(b * LI + px)) * CCH + sub * 32;
        float a[32];
#pragma unroll
        for (int k = 0; k < 4; ++k) {
            short8 v = *(const short8*)(pa + k * 8);
#pragma unroll
            for (int e = 0; e < 8; ++e) a[k * 8 + e] = bf2f(v[e]);
        }
#pragma unroll
        for (int d = 1; d <= 3 - I; ++d) {
            const int RJ = RI >> d;
            const int LJ = RJ * RJ;
            const int pxj = (h >> d) * RJ + (w >> d);
            const short* pb = uj[d - 1] + ((size_t)(b * LJ + pxj)) * CCH + sub * 32;
            float s = 0.f;
#pragma unroll
            for (int k = 0; k < 4; ++k) {
                short8 v = *(const short8*)(pb + k * 8);
#pragma unroll
                for (int e = 0; e < 8; ++e) s += a[k * 8 + e] * bf2f(v[e]);
            }
            acc[d - 1] += s;
        }
    }
}

__global__ __launch_bounds__(256) void pair_dots(
    const short* __restrict__ u0, const short* __restrict__ u1,
    const short* __restrict__ u2, const short* __restrict__ u3,
    float* __restrict__ sums) {
    const int i = blockIdx.y;          // fine scale of the pass: 0,1,2
    const int b = blockIdx.z;
    const int t = threadIdx.x;
    const int lane = t & 63;
    const int wav = t >> 6;
    const int wave_id = blockIdx.x * 4 + wav;   // 0..199
    const int pg = lane >> 3;
    const int sub = lane & 7;

    float acc[3] = {0.f, 0.f, 0.f};
    if (i == 0)      pair_body<0>(u0, u1, u2, u3, b, wave_id, pg, sub, acc);
    else if (i == 1) pair_body<1>(u1, u2, u3, u3, b, wave_id, pg, sub, acc);
    else             pair_body<2>(u2, u3, u3, u3, b, wave_id, pg, sub, acc);

    __shared__ float red[4][3];
#pragma unroll
    for (int p = 0; p < 3; ++p) {
        float v = acc[p];
        v += __shfl_xor(v, 1);  v += __shfl_xor(v, 2);  v += __shfl_xor(v, 4);
        v += __shfl_xor(v, 8);  v += __shfl_xor(v, 16); v += __shfl_xor(v, 32);
        if (lane == 0) red[wav][p] = v;
    }
    __syncthreads();
    const int npairs = 3 - i;
    const int base = (i == 0) ? 0 : (i == 1) ? 3 : 5;
    if (t < npairs) {
        float s = red[0][t] + red[1][t] + red[2][t] + red[3][t];
        atomicAdd(&sums[b * 6 + base + t], s);
    }
}

// ---------- Softmax over j for each (b,i) row ----------
__global__ void softmax4(const float* __restrict__ sums, float* __restrict__ out) {
    int t = threadIdx.x;
    if (t >= 128) return;
    int b = t >> 4, i = (t >> 2) & 3, j = t & 3;
    float a[4];
#pragma unroll
    for (int jj = 0; jj < 4; ++jj) {
        if (jj == i) { a[jj] = 1.0f; continue; }
        int lo = i < jj ? i : jj;
        int hi = i < jj ? jj : i;
        int pidx;
        if (lo == 0) pidx = hi - 1;          // (0,1)=0 (0,2)=1 (0,3)=2
        else if (lo == 1) pidx = 1 + hi;     // (1,2)=3 (1,3)=4
        else pidx = 5;                       // (2,3)=5
        int rf = 80 >> lo;
        a[jj] = sums[b * 6 + pidx] / (float)(rf * rf);
    }
    float m = fmaxf(fmaxf(a[0], a[1]), fmaxf(a[2], a[3]));
    float e0 = expf(a[0] - m), e1 = expf(a[1] - m), e2 = expf(a[2] - m), e3 = expf(a[3] - m);
    float sum = e0 + e1 + e2 + e3;
    float ev = (j == 0) ? e0 : (j == 1) ? e1 : (j == 2) ? e2 : e3;
    out[t] = ev / sum;
}

extern "C" void kernel_launch(void* const* d_in, const int* in_sizes, int n_in,
                              void* d_out, int out_size, void* d_ws, size_t ws_size,
                              hipStream_t stream) {
    // setup_inputs dict insertion order: f0,w0,b0, f1,w1,b1, f2,w2,b2, f3,w3,b3
    const float* f[4]  = {(const float*)d_in[0], (const float*)d_in[3],
                          (const float*)d_in[6], (const float*)d_in[9]};
    const float* w[4]  = {(const float*)d_in[1], (const float*)d_in[4],
                          (const float*)d_in[7], (const float*)d_in[10]};
    const float* bs[4] = {(const float*)d_in[2], (const float*)d_in[5],
                          (const float*)d_in[8], (const float*)d_in[11]};

    const int Ls[4] = {6400, 1600, 400, 100};
    char* ws = (char*)d_ws;
    size_t off = 0;
    short* u[4];
    for (int s = 0; s < 4; ++s) {
        u[s] = (short*)(ws + off);
        off += (size_t)8 * CCH * Ls[s] * sizeof(short);
    }
    short* wp = (short*)(ws + off); off += 4 * 65536 * sizeof(short);
    float* sums = (float*)(ws + off);   // 48 floats

    hipMemsetAsync(sums, 0, 64 * sizeof(float), stream);

    pack_w<<<dim3(32, 4), 256, 0, stream>>>(w[0], w[1], w[2], w[3], wp);

    proj_norm<<<1072, 256, 0, stream>>>(f[0], f[1], f[2], f[3], wp,
                                        bs[0], bs[1], bs[2], bs[3],
                                        u[0], u[1], u[2], u[3]);

    pair_dots<<<dim3(50, 3, 8), 256, 0, stream>>>(u[0], u[1], u[2], u[3], sums);

    softmax4<<<1, 128, 0, stream>>>(sums, (float*)d_out);
}